// Round 4
// baseline (10783.407 us; speedup 1.0000x reference)
//
#include <hip/hip_runtime.h>
#include <cmath>

// Problem constants
static constexpr int Bb  = 4;
static constexpr int S   = 2048;
static constexpr int DIN = 4096;
static constexpr int P   = 512;    // D_PROJ == D_MEM
static constexpr int AST = 512;    // assistant_start
static constexpr int TR  = 1536;   // run length
static constexpr int NWG = 32;     // scan workgroups (16 U-columns each)
#define DTC (1.0f/1535.0f)

// Workspace layout (float element offsets)
static constexpr size_t SZ      = (size_t)Bb * S * P;          // 4,194,304
static constexpr size_t GXSZ    = (size_t)TR * Bb * P;         // 3,145,728
static constexpr size_t OFF_Q   = 0;
static constexpr size_t OFF_K   = SZ;
static constexpr size_t OFF_V   = 2 * SZ;
static constexpr size_t OFF_GXZ = 0;                           // reuses Q/K/V after attention
static constexpr size_t OFF_GXR = GXSZ;
static constexpr size_t OFF_GXH = 2 * GXSZ;
static constexpr size_t OFF_FEAT= 3 * GXSZ + (size_t)(TR + 1) * Bb * P;
static constexpr size_t OFF_SC  = OFF_FEAT + SZ;               // scores; tagged bufs + hist live here in scan phase
static constexpr size_t OFF_HIST= OFF_SC + 16384;              // after hT/rhT (8192 u64 = 16384 floats)

#define INNER16 \
  acc[0][0] += af.x*bf.x; acc[0][1] += af.x*bf.y; acc[0][2] += af.x*bf.z; acc[0][3] += af.x*bf.w; \
  acc[1][0] += af.y*bf.x; acc[1][1] += af.y*bf.y; acc[1][2] += af.y*bf.z; acc[1][3] += af.y*bf.w; \
  acc[2][0] += af.z*bf.x; acc[2][1] += af.z*bf.y; acc[2][2] += af.z*bf.z; acc[2][3] += af.z*bf.w; \
  acc[3][0] += af.w*bf.x; acc[3][1] += af.w*bf.y; acc[3][2] += af.w*bf.z; acc[3][3] += af.w*bf.w;

// Fill tagged-word buffers with an impossible tag (0xFFFFFFFF) so stale data
// from a previous launch/graph-replay can never match a step tag.
__global__ __launch_bounds__(256) void k_tagclear(unsigned long long* p, int n) {
  int i = blockIdx.x * 256 + threadIdx.x;
  if (i < n) p[i] = 0xFFFFFFFF00000000ULL;
}

// ---------------- QKV projection: (8192 x 4096) @ (4096 x 512) + bias, z selects Q/K/V
__global__ __launch_bounds__(256) void k_qkv(
    const float* __restrict__ x,
    const float* __restrict__ W0, const float* __restrict__ W1, const float* __restrict__ W2,
    const float* __restrict__ b0, const float* __restrict__ b1, const float* __restrict__ b2,
    float* __restrict__ O0, float* __restrict__ O1, float* __restrict__ O2)
{
  __shared__ float As[32][68];  // transposed A tile: As[k][m]
  __shared__ float Bs[32][64];
  const int z = blockIdx.z;
  const float* W    = (z == 0) ? W0 : (z == 1) ? W1 : W2;
  const float* bias = (z == 0) ? b0 : (z == 1) ? b1 : b2;
  float* Out        = (z == 0) ? O0 : (z == 1) ? O1 : O2;
  const int tid = threadIdx.x;
  const int m0 = blockIdx.y * 64, n0 = blockIdx.x * 64;
  const int tm = tid >> 4, tn = tid & 15;
  const int la_m = tid >> 3;
  const int la_k = (tid & 7) << 2;
  const int lb_k = tid >> 4;
  const int lb_n = (tid & 15) << 2;
  float acc[4][4] = {};
  for (int k0 = 0; k0 < DIN; k0 += 32) {
#pragma unroll
    for (int pp = 0; pp < 2; ++pp) {
      int m = la_m + pp * 32;
      float4 v = *(const float4*)(x + (size_t)(m0 + m) * DIN + k0 + la_k);
      As[la_k + 0][m] = v.x; As[la_k + 1][m] = v.y; As[la_k + 2][m] = v.z; As[la_k + 3][m] = v.w;
    }
#pragma unroll
    for (int pp = 0; pp < 2; ++pp) {
      int k = lb_k + pp * 16;
      *(float4*)&Bs[k][lb_n] = *(const float4*)(W + (size_t)(k0 + k) * P + n0 + lb_n);
    }
    __syncthreads();
#pragma unroll
    for (int kk = 0; kk < 32; ++kk) {
      float4 af = *(float4*)&As[kk][tm << 2];
      float4 bf = *(float4*)&Bs[kk][tn << 2];
      INNER16
    }
    __syncthreads();
  }
  float4 bv = *(const float4*)(bias + n0 + (tn << 2));
#pragma unroll
  for (int i = 0; i < 4; ++i) {
    int row = m0 + (tm << 2) + i;
    float4 o = make_float4(acc[i][0] + bv.x, acc[i][1] + bv.y, acc[i][2] + bv.z, acc[i][3] + bv.w);
    *(float4*)(Out + (size_t)row * P + n0 + (tn << 2)) = o;
  }
}

// ---------------- scores = Q @ K^T / scale, causal mask (only tiles jt <= qt computed)
__global__ __launch_bounds__(256) void k_scores(
    const float* __restrict__ Q, const float* __restrict__ Km, float* __restrict__ Sc)
{
  const int jt = blockIdx.x, qt = blockIdx.y, b = blockIdx.z;
  if (jt > qt) return;
  __shared__ float As[32][68];  // Q^T: As[k][i]
  __shared__ float Bs[32][68];  // K^T: Bs[k][j]
  const float* Qb = Q + (size_t)b * S * P;
  const float* Kb = Km + (size_t)b * S * P;
  const int tid = threadIdx.x;
  const int i0 = qt * 64, j0 = jt * 64;
  const int tm = tid >> 4, tn = tid & 15;
  const int lr = tid >> 3;
  const int lk = (tid & 7) << 2;
  float acc[4][4] = {};
  for (int k0 = 0; k0 < P; k0 += 32) {
#pragma unroll
    for (int pp = 0; pp < 2; ++pp) {
      int r = lr + pp * 32;
      float4 v = *(const float4*)(Qb + (size_t)(i0 + r) * P + k0 + lk);
      As[lk + 0][r] = v.x; As[lk + 1][r] = v.y; As[lk + 2][r] = v.z; As[lk + 3][r] = v.w;
      float4 w = *(const float4*)(Kb + (size_t)(j0 + r) * P + k0 + lk);
      Bs[lk + 0][r] = w.x; Bs[lk + 1][r] = w.y; Bs[lk + 2][r] = w.z; Bs[lk + 3][r] = w.w;
    }
    __syncthreads();
#pragma unroll
    for (int kk = 0; kk < 32; ++kk) {
      float4 af = *(float4*)&As[kk][tm << 2];
      float4 bf = *(float4*)&Bs[kk][tn << 2];
      INNER16
    }
    __syncthreads();
  }
  const float invs = 0.04419417382f;  // 1/sqrt(512+1e-6)
#pragma unroll
  for (int i = 0; i < 4; ++i) {
    int ig = i0 + (tm << 2) + i;
    float v0 = acc[i][0] * invs, v1 = acc[i][1] * invs, v2 = acc[i][2] * invs, v3 = acc[i][3] * invs;
    int jg = j0 + (tn << 2);
    if (jg + 0 > ig) v0 = -1e9f;
    if (jg + 1 > ig) v1 = -1e9f;
    if (jg + 2 > ig) v2 = -1e9f;
    if (jg + 3 > ig) v3 = -1e9f;
    *(float4*)(Sc + (size_t)b * S * S + (size_t)ig * S + jg) = make_float4(v0, v1, v2, v3);
  }
}

// ---------------- row softmax over [0, i], zero-fill to end of diagonal tile (in place)
__global__ __launch_bounds__(256) void k_softmax(float* __restrict__ Sc)
{
  const int i = blockIdx.x, b = blockIdx.y;
  float* row = Sc + (size_t)b * S * S + (size_t)i * S;
  __shared__ float sv[2048];
  __shared__ float red[256];
  const int tid = threadIdx.x;
  const int len = i + 1;
  float lmax = -1e30f;
  for (int k = tid; k < len; k += 256) { float v = row[k]; sv[k] = v; lmax = fmaxf(lmax, v); }
  red[tid] = lmax; __syncthreads();
  for (int s = 128; s > 0; s >>= 1) { if (tid < s) red[tid] = fmaxf(red[tid], red[tid + s]); __syncthreads(); }
  const float m = red[0]; __syncthreads();
  float lsum = 0.f;
  for (int k = tid; k < len; k += 256) { float e = expf(sv[k] - m); sv[k] = e; lsum += e; }
  red[tid] = lsum; __syncthreads();
  for (int s = 128; s > 0; s >>= 1) { if (tid < s) red[tid] += red[tid + s]; __syncthreads(); }
  const float inv = 1.0f / red[0];
  for (int k = tid; k < len; k += 256) row[k] = sv[k] * inv;
  const int tail = ((i >> 6) + 1) << 6;
  for (int k = len + tid; k < tail; k += 256) row[k] = 0.f;
}

// ---------------- feat = attn @ V (skip upper-triangle tiles)
__global__ __launch_bounds__(256) void k_attnv(
    const float* __restrict__ At, const float* __restrict__ V, float* __restrict__ F)
{
  __shared__ float As[32][68];
  __shared__ float Bs[32][64];
  const int qt = blockIdx.y, b = blockIdx.z;
  const float* Ab = At + (size_t)b * S * S;
  const float* Vb = V + (size_t)b * S * P;
  const int tid = threadIdx.x;
  const int m0 = qt * 64, n0 = blockIdx.x * 64;
  const int tm = tid >> 4, tn = tid & 15;
  const int la_m = tid >> 3;
  const int la_k = (tid & 7) << 2;
  const int lb_k = tid >> 4;
  const int lb_n = (tid & 15) << 2;
  float acc[4][4] = {};
  const int kext = (qt + 1) * 64;
  for (int k0 = 0; k0 < kext; k0 += 32) {
#pragma unroll
    for (int pp = 0; pp < 2; ++pp) {
      int m = la_m + pp * 32;
      float4 v = *(const float4*)(Ab + (size_t)(m0 + m) * S + k0 + la_k);
      As[la_k + 0][m] = v.x; As[la_k + 1][m] = v.y; As[la_k + 2][m] = v.z; As[la_k + 3][m] = v.w;
    }
#pragma unroll
    for (int pp = 0; pp < 2; ++pp) {
      int k = lb_k + pp * 16;
      *(float4*)&Bs[k][lb_n] = *(const float4*)(Vb + (size_t)(k0 + k) * P + n0 + lb_n);
    }
    __syncthreads();
#pragma unroll
    for (int kk = 0; kk < 32; ++kk) {
      float4 af = *(float4*)&As[kk][tm << 2];
      float4 bf = *(float4*)&Bs[kk][tn << 2];
      INNER16
    }
    __syncthreads();
  }
#pragma unroll
  for (int i = 0; i < 4; ++i) {
    int row = m0 + (tm << 2) + i;
    *(float4*)(F + (size_t)b * S * P + (size_t)row * P + n0 + (tn << 2)) =
        make_float4(acc[i][0], acc[i][1], acc[i][2], acc[i][3]);
  }
}

// ---------------- gx = feat_assist @ {Wz,Wr,Wh} + bias; output layout [t][b][j]
__global__ __launch_bounds__(256) void k_gx(
    const float* __restrict__ feat,
    const float* __restrict__ Wz, const float* __restrict__ Wr, const float* __restrict__ Wh,
    const float* __restrict__ bz, const float* __restrict__ br, const float* __restrict__ bh,
    float* __restrict__ gz, float* __restrict__ gr, float* __restrict__ gh)
{
  __shared__ float As[32][68];
  __shared__ float Bs[32][64];
  const int z = blockIdx.z;
  const float* W    = (z == 0) ? Wz : (z == 1) ? Wr : Wh;
  const float* bias = (z == 0) ? bz : (z == 1) ? br : bh;
  float* Out        = (z == 0) ? gz : (z == 1) ? gr : gh;
  const int tid = threadIdx.x;
  const int m0 = blockIdx.y * 64, n0 = blockIdx.x * 64;
  const int bb = m0 / TR;
  const int t0 = m0 - bb * TR;
  const float* Arow = feat + ((size_t)(bb * S + AST + t0)) * P;  // 64 consecutive rows
  const int tm = tid >> 4, tn = tid & 15;
  const int la_m = tid >> 3;
  const int la_k = (tid & 7) << 2;
  const int lb_k = tid >> 4;
  const int lb_n = (tid & 15) << 2;
  float acc[4][4] = {};
  for (int k0 = 0; k0 < P; k0 += 32) {
#pragma unroll
    for (int pp = 0; pp < 2; ++pp) {
      int m = la_m + pp * 32;
      float4 v = *(const float4*)(Arow + (size_t)m * P + k0 + la_k);
      As[la_k + 0][m] = v.x; As[la_k + 1][m] = v.y; As[la_k + 2][m] = v.z; As[la_k + 3][m] = v.w;
    }
#pragma unroll
    for (int pp = 0; pp < 2; ++pp) {
      int k = lb_k + pp * 16;
      *(float4*)&Bs[k][lb_n] = *(const float4*)(W + (size_t)(k0 + k) * P + n0 + lb_n);
    }
    __syncthreads();
#pragma unroll
    for (int kk = 0; kk < 32; ++kk) {
      float4 af = *(float4*)&As[kk][tm << 2];
      float4 bf = *(float4*)&Bs[kk][tn << 2];
      INNER16
    }
    __syncthreads();
  }
  float4 bv = *(const float4*)(bias + n0 + (tn << 2));
#pragma unroll
  for (int i = 0; i < 4; ++i) {
    int t = t0 + (tm << 2) + i;
    float4 o = make_float4(acc[i][0] + bv.x, acc[i][1] + bv.y, acc[i][2] + bv.z, acc[i][3] + bv.w);
    *(float4*)(Out + ((size_t)t * 4 + bb) * P + n0 + (tn << 2)) = o;
  }
}

// ---------------- attention pooling over prefix + h0; writes tagged h(0) (tag=0)
__global__ __launch_bounds__(256) void k_pool(
    const float* __restrict__ feat, const float* __restrict__ Wscore,
    const float* __restrict__ Wp2h, const float* __restrict__ bp2h,
    unsigned long long* __restrict__ hT)
{
  const int b = blockIdx.x;
  const float* fb = feat + (size_t)b * S * P;  // prefix rows 0..511
  __shared__ float sw[512];
  __shared__ float pool[512];
  __shared__ float red[256];
  const int tid = threadIdx.x;
  for (int u = tid; u < 512; u += 256) {
    float s = 0.f;
    for (int p4 = 0; p4 < P; p4 += 4) {
      float4 f = *(const float4*)(fb + (size_t)u * P + p4);
      float4 w = *(const float4*)(Wscore + p4);
      s += f.x * w.x + f.y * w.y + f.z * w.z + f.w * w.w;
    }
    sw[u] = s;
  }
  __syncthreads();
  float lm = fmaxf(sw[tid], sw[tid + 256]);
  red[tid] = lm; __syncthreads();
  for (int s = 128; s > 0; s >>= 1) { if (tid < s) red[tid] = fmaxf(red[tid], red[tid + s]); __syncthreads(); }
  const float m = red[0]; __syncthreads();
  float e0 = expf(sw[tid] - m), e1 = expf(sw[tid + 256] - m);
  sw[tid] = e0; sw[tid + 256] = e1;
  red[tid] = e0 + e1; __syncthreads();
  for (int s = 128; s > 0; s >>= 1) { if (tid < s) red[tid] += red[tid + s]; __syncthreads(); }
  const float inv = 1.0f / red[0];
  __syncthreads();
  sw[tid] *= inv; sw[tid + 256] *= inv;
  __syncthreads();
  for (int p = tid; p < P; p += 256) {
    float a = 0.f;
    for (int u = 0; u < 512; ++u) a += sw[u] * fb[(size_t)u * P + p];
    pool[p] = a;
  }
  __syncthreads();
  for (int j = tid; j < P; j += 256) {
    float a = bp2h[j];
    for (int p = 0; p < P; ++p) a += pool[p] * Wp2h[(size_t)p * P + j];
    // tagged word: tag (hi) = 0, value (lo) = f32 bits of h0
    hT[(size_t)b * 512 + j] = (unsigned long long)__float_as_uint(tanhf(a));
  }
}

// xor-butterfly reduce of 4 batch accumulators across a 2^LOG2N-lane group.
// Result: group-lane l holds acc[l&3] summed over the whole group.
template<int LOG2N>
__device__ __forceinline__ float xreduce4(float a0, float a1, float a2, float a3, int lane)
{
  float s01 = (lane & 1) ? a0 : a1;
  float r01 = __shfl_xor(s01, 1);
  float x0  = ((lane & 1) ? a1 : a0) + r01;
  float s23 = (lane & 1) ? a2 : a3;
  float r23 = __shfl_xor(s23, 1);
  float x2  = ((lane & 1) ? a3 : a2) + r23;
  float s   = (lane & 2) ? x0 : x2;
  float r   = __shfl_xor(s, 2);
  float v   = ((lane & 2) ? x2 : x0) + r;
#pragma unroll
  for (int m = 4; m < (1 << LOG2N); m <<= 1) v += __shfl_xor(v, m);
  return v;
}

// ---------------- persistent GRU scan: 32 WGs x 512 threads, 16 U-columns each.
// 2 barriers per step. Cross-WG sync: tagged 8-byte words ({step : f32}) in a
// depth-2 double buffer at AGENT scope; each thread polls only its own 4
// single-writer words. U-matrix slices live in registers. Logit work is
// off-loop (ho streamed to hist; k_outred does the dot).
// Cross-step LDS races are prevented by double-buffering rhb/zloc/hploc on
// (t&1): a wave reaches phase A of t+2 only after ALL waves published h(t+2),
// i.e. after all waves finished phase B of t+1. hb is safe single-buffered:
// its deposits (pre-B1 of t+1) follow B2 of t, which follows all phase-A reads.
// Hang-safety: publishes are separated from same-thread polls by compiler
// memory barriers; issued stores drain independently of spinning loads.
__global__ __launch_bounds__(512) void k_scan(
    const float* __restrict__ Uz, const float* __restrict__ Ur, const float* __restrict__ Uh,
    const float* __restrict__ gz, const float* __restrict__ gr, const float* __restrict__ gh,
    unsigned long long* __restrict__ hT, unsigned long long* __restrict__ rhT,
    float* __restrict__ hist)
{
  __shared__ float Us[3][2][8][520];
  __shared__ float hb[4][516];
  __shared__ float rhb[2][4][516];
  __shared__ float zloc[2][16][4];
  __shared__ float hploc[2][16][4];
  const int wg = blockIdx.x;
  const int tid = threadIdx.x;
  const int j0 = wg * 16;

  for (int idx = tid; idx < 3 * 512 * 16; idx += 512) {
    int mt = idx >> 13;                // 8192 elements per matrix
    int rem = idx & 8191;
    int i = rem >> 4, c = rem & 15;
    const float* U = (mt == 0) ? Uz : (mt == 1) ? Ur : Uh;
    Us[mt][c >> 3][c & 7][i] = U[(size_t)i * P + j0 + c];
  }

  // phase-A role: gate g (0=z,1=r), column cAa (0..15), 16 lanes per column
  const int gA  = tid >> 8;
  const int cAa = (tid >> 4) & 15;
  const int ipA = tid & 15;
  const float* UcA = &Us[gA][cAa >> 3][cAa & 7][0];
  // phase-B role: column cBb (0..15), 32 lanes per column
  const int cBb = tid >> 5;
  const int ipB = tid & 31;
  const float* UcB = &Us[2][cBb >> 3][cBb & 7][0];
  // poll role: 4 consecutive floats, single writer WG
  const int pb = tid >> 7;
  const int pj = (tid << 2) & 511;
  __syncthreads();

  // U slices into registers (LDS -> VGPR, one-time)
  float4 uA[8], uB[4];
#pragma unroll
  for (int n = 0; n < 8; ++n) uA[n] = *(const float4*)&UcA[((n << 4) | ipA) << 2];
#pragma unroll
  for (int n = 0; n < 4; ++n) uB[n] = *(const float4*)&UcB[((n << 5) | ipB) << 2];

  for (int t = 0; t < TR; ++t) {
    const int sl = t & 1;
    const unsigned long long wtag = (unsigned long long)(unsigned)t << 32;
    // prefetch gx operands (L2 loads, hidden under the h poll)
    float gxa = 0.f;
    if (ipA < 4) gxa = (gA ? gr : gz)[((size_t)t * 4 + ipA) * P + j0 + cAa];
    float ghv = 0.f;
    if (ipB < 4) ghv = gh[((size_t)t * 4 + ipB) * P + j0 + cBb];

    // gather h(t): poll own 4 tagged words, deposit into hb
    {
      const unsigned long long* src = hT + (size_t)sl * 2048 + ((size_t)tid << 2);
      unsigned long long u0, u1, u2, u3;
      do {
        u0 = __hip_atomic_load(src + 0, __ATOMIC_RELAXED, __HIP_MEMORY_SCOPE_AGENT);
        u1 = __hip_atomic_load(src + 1, __ATOMIC_RELAXED, __HIP_MEMORY_SCOPE_AGENT);
        u2 = __hip_atomic_load(src + 2, __ATOMIC_RELAXED, __HIP_MEMORY_SCOPE_AGENT);
        u3 = __hip_atomic_load(src + 3, __ATOMIC_RELAXED, __HIP_MEMORY_SCOPE_AGENT);
      } while ((((u0 ^ wtag) | (u1 ^ wtag) | (u2 ^ wtag) | (u3 ^ wtag)) >> 32) != 0ull);
      *(float4*)&hb[pb][pj] = make_float4(
          __uint_as_float((unsigned)u0), __uint_as_float((unsigned)u1),
          __uint_as_float((unsigned)u2), __uint_as_float((unsigned)u3));
    }
    __syncthreads();   // B1: hb holds h(t)

    // phase A: z,r for this WG's 16 columns (one column per 16-lane group)
    {
      float a0 = 0.f, a1 = 0.f, a2 = 0.f, a3 = 0.f;
#pragma unroll
      for (int n = 0; n < 8; ++n) {
        int off = ((n << 4) | ipA) << 2;
        float4 u   = uA[n];
        float4 h0v = *(const float4*)&hb[0][off];
        float4 h1v = *(const float4*)&hb[1][off];
        float4 h2v = *(const float4*)&hb[2][off];
        float4 h3v = *(const float4*)&hb[3][off];
        a0 += u.x * h0v.x + u.y * h0v.y + u.z * h0v.z + u.w * h0v.w;
        a1 += u.x * h1v.x + u.y * h1v.y + u.z * h1v.z + u.w * h1v.w;
        a2 += u.x * h2v.x + u.y * h2v.y + u.z * h2v.z + u.w * h2v.w;
        a3 += u.x * h3v.x + u.y * h3v.y + u.z * h3v.z + u.w * h3v.w;
      }
      float v = xreduce4<4>(a0, a1, a2, a3, ipA);
      if (ipA < 4) {
        const int b = ipA;
        float s = gxa + v;
        float sg = 1.0f / (1.0f + expf(-s));
        if (gA == 0) {
          zloc[sl][cAa][b] = sg;
        } else {
          float hov = hb[b][j0 + cAa];
          hploc[sl][cAa][b] = hov;
          unsigned long long w = wtag | (unsigned long long)__float_as_uint(sg * hov);
          __hip_atomic_store(rhT + (size_t)sl * 2048 + (size_t)b * 512 + j0 + cAa,
                             w, __ATOMIC_RELAXED, __HIP_MEMORY_SCOPE_AGENT);
        }
      }
      asm volatile("" ::: "memory");  // rh publish stays above the rh poll
    }

    // gather rh(t): poll own 4 tagged words, deposit into rhb[sl]
    {
      const unsigned long long* src = rhT + (size_t)sl * 2048 + ((size_t)tid << 2);
      unsigned long long r0, r1, r2, r3;
      do {
        r0 = __hip_atomic_load(src + 0, __ATOMIC_RELAXED, __HIP_MEMORY_SCOPE_AGENT);
        r1 = __hip_atomic_load(src + 1, __ATOMIC_RELAXED, __HIP_MEMORY_SCOPE_AGENT);
        r2 = __hip_atomic_load(src + 2, __ATOMIC_RELAXED, __HIP_MEMORY_SCOPE_AGENT);
        r3 = __hip_atomic_load(src + 3, __ATOMIC_RELAXED, __HIP_MEMORY_SCOPE_AGENT);
      } while ((((r0 ^ wtag) | (r1 ^ wtag) | (r2 ^ wtag) | (r3 ^ wtag)) >> 32) != 0ull);
      *(float4*)&rhb[sl][pb][pj] = make_float4(
          __uint_as_float((unsigned)r0), __uint_as_float((unsigned)r1),
          __uint_as_float((unsigned)r2), __uint_as_float((unsigned)r3));
    }
    __syncthreads();   // B2: zloc/hploc/rhb[sl] ready; all hb(h) reads done

    // phase B: h_hat, h_new, h_out; publish tagged h(t+1); stream ho to hist
    {
      float p0 = 0.f, p1 = 0.f, p2 = 0.f, p3 = 0.f;
      const float* rb0 = &rhb[sl][0][0];
      const float* rb1 = &rhb[sl][1][0];
      const float* rb2 = &rhb[sl][2][0];
      const float* rb3 = &rhb[sl][3][0];
#pragma unroll
      for (int n = 0; n < 4; ++n) {
        int off = ((n << 5) | ipB) << 2;
        float4 u   = uB[n];
        float4 h0v = *(const float4*)&rb0[off];
        float4 h1v = *(const float4*)&rb1[off];
        float4 h2v = *(const float4*)&rb2[off];
        float4 h3v = *(const float4*)&rb3[off];
        p0 += u.x * h0v.x + u.y * h0v.y + u.z * h0v.z + u.w * h0v.w;
        p1 += u.x * h1v.x + u.y * h1v.y + u.z * h1v.z + u.w * h1v.w;
        p2 += u.x * h2v.x + u.y * h2v.y + u.z * h2v.z + u.w * h2v.w;
        p3 += u.x * h3v.x + u.y * h3v.y + u.z * h3v.z + u.w * h3v.w;
      }
      float pv = xreduce4<5>(p0, p1, p2, p3, ipB);
      if (ipB < 4) {
        const int b = ipB;
        float hhat = tanhf(ghv + pv);
        float z = zloc[sl][cBb][b], hp = hploc[sl][cBb][b];
        float hn = (1.0f - z) * hp + z * hhat;
        float dtv = (t == 0) ? 0.f : DTC;
        float ho = hn + dtv * (hn - hp);
        unsigned long long w = ((unsigned long long)(unsigned)(t + 1) << 32)
                             | (unsigned long long)__float_as_uint(ho);
        __hip_atomic_store(hT + (size_t)((t + 1) & 1) * 2048 + (size_t)b * 512 + j0 + cBb,
                           w, __ATOMIC_RELAXED, __HIP_MEMORY_SCOPE_AGENT);
        hist[((size_t)t * 4 + b) * 512 + j0 + cBb] = ho;   // fire-and-forget
      }
      asm volatile("" ::: "memory");  // h publish stays above next h poll
    }
    // no barrier: next-step hb deposits are safe (B2 ordered all hb reads),
    // rhb/zloc/hploc flip buffers on (t&1)
  }
}

// ---------------- final logits: out[b][t] = bmem + hist[t,b,:] @ Wmem
__global__ __launch_bounds__(256) void k_outred(
    const float* __restrict__ hist, const float* __restrict__ Wmem,
    const float* __restrict__ bmem, float* __restrict__ out)
{
  int i = blockIdx.x * 256 + threadIdx.x;
  if (i < Bb * TR) {
    int b = i / TR, t = i - b * TR;
    const float* hrow = hist + ((size_t)t * 4 + b) * 512;
    float s = 0.f;
    for (int j = 0; j < 512; j += 4) {
      float4 h = *(const float4*)(hrow + j);
      float4 w = *(const float4*)(Wmem + j);
      s += h.x * w.x + h.y * w.y + h.z * w.z + h.w * w.w;
    }
    out[i] = s + bmem[0];
  }
}

extern "C" void kernel_launch(void* const* d_in, const int* in_sizes, int n_in,
                              void* d_out, int out_size, void* d_ws, size_t ws_size,
                              hipStream_t stream)
{
  const float* x      = (const float*)d_in[0];
  const float* Wq     = (const float*)d_in[1];
  const float* bq     = (const float*)d_in[2];
  const float* Wk     = (const float*)d_in[3];
  const float* bk     = (const float*)d_in[4];
  const float* Wv     = (const float*)d_in[5];
  const float* bv     = (const float*)d_in[6];
  const float* Wz     = (const float*)d_in[7];
  const float* Uz     = (const float*)d_in[8];
  const float* bz     = (const float*)d_in[9];
  const float* Wr     = (const float*)d_in[10];
  const float* Ur     = (const float*)d_in[11];
  const float* br     = (const float*)d_in[12];
  const float* Wh     = (const float*)d_in[13];
  const float* Uh     = (const float*)d_in[14];
  const float* bh     = (const float*)d_in[15];
  const float* Wmem   = (const float*)d_in[16];
  const float* bmem   = (const float*)d_in[17];
  const float* Wp2h   = (const float*)d_in[18];
  const float* bp2h   = (const float*)d_in[19];
  const float* Wscore = (const float*)d_in[20];

  float* ws  = (float*)d_ws;
  float* out = (float*)d_out;
  float* Q    = ws + OFF_Q;
  float* Kk   = ws + OFF_K;
  float* V    = ws + OFF_V;
  float* feat = ws + OFF_FEAT;
  float* Sc   = ws + OFF_SC;
  float* gz   = ws + OFF_GXZ;
  float* gr   = ws + OFF_GXR;
  float* gh   = ws + OFF_GXH;
  // Tagged sync buffers + ho history live at the head of the
  // (dead-after-attnv) scores region.
  unsigned long long* hT   = (unsigned long long*)(ws + OFF_SC);
  unsigned long long* rhT  = hT + 4096;
  float*              hist = ws + OFF_HIST;

  k_qkv<<<dim3(8, 128, 3), 256, 0, stream>>>(x, Wq, Wk, Wv, bq, bk, bv, Q, Kk, V);
  k_scores<<<dim3(32, 32, 4), 256, 0, stream>>>(Q, Kk, Sc);
  k_softmax<<<dim3(2048, 4), 256, 0, stream>>>(Sc);
  k_attnv<<<dim3(8, 32, 4), 256, 0, stream>>>(Sc, V, feat);
  // clear stale tags AFTER the scores region is dead, BEFORE k_pool writes h0
  k_tagclear<<<dim3(32), 256, 0, stream>>>(hT, 8192);
  k_gx<<<dim3(8, 96, 3), 256, 0, stream>>>(feat, Wz, Wr, Wh, bz, br, bh, gz, gr, gh);
  k_pool<<<dim3(4), 256, 0, stream>>>(feat, Wscore, Wp2h, bp2h, hT);
  k_scan<<<dim3(NWG), 512, 0, stream>>>(Uz, Ur, Uh, gz, gr, gh, hT, rhT, hist);
  k_outred<<<dim3(24), 256, 0, stream>>>(hist, Wmem, bmem, out);
}

// Round 5
// 9320.787 us; speedup vs baseline: 1.1569x; 1.1569x over previous
//
#include <hip/hip_runtime.h>
#include <cmath>

// Problem constants
static constexpr int Bb  = 4;
static constexpr int S   = 2048;
static constexpr int DIN = 4096;
static constexpr int P   = 512;    // D_PROJ == D_MEM
static constexpr int AST = 512;    // assistant_start
static constexpr int TR  = 1536;   // run length
static constexpr int NWG = 32;     // scan workgroups (16 U-columns each)
#define DTC (1.0f/1535.0f)

// Workspace layout (float element offsets)
static constexpr size_t SZ      = (size_t)Bb * S * P;          // 4,194,304
static constexpr size_t GXSZ    = (size_t)TR * Bb * P;         // 3,145,728
static constexpr size_t OFF_Q   = 0;
static constexpr size_t OFF_K   = SZ;
static constexpr size_t OFF_V   = 2 * SZ;
static constexpr size_t OFF_GXZ = 0;                           // reuses Q/K/V after attention
static constexpr size_t OFF_GXR = GXSZ;
static constexpr size_t OFF_GXH = 2 * GXSZ;
static constexpr size_t OFF_FEAT= 3 * GXSZ + (size_t)(TR + 1) * Bb * P;
static constexpr size_t OFF_SC  = OFF_FEAT + SZ;               // scores; tagged bufs + hist live here in scan phase
static constexpr size_t OFF_HIST= OFF_SC + 16384;              // after hT/rhT (8192 u64 = 16384 floats)

#define INNER16 \
  acc[0][0] += af.x*bf.x; acc[0][1] += af.x*bf.y; acc[0][2] += af.x*bf.z; acc[0][3] += af.x*bf.w; \
  acc[1][0] += af.y*bf.x; acc[1][1] += af.y*bf.y; acc[1][2] += af.y*bf.z; acc[1][3] += af.y*bf.w; \
  acc[2][0] += af.z*bf.x; acc[2][1] += af.z*bf.y; acc[2][2] += af.z*bf.z; acc[2][3] += af.z*bf.w; \
  acc[3][0] += af.w*bf.x; acc[3][1] += af.w*bf.y; acc[3][2] += af.w*bf.z; acc[3][3] += af.w*bf.w;

// Fill tagged-word buffers with an impossible tag (0xFFFFFFFF) so stale data
// from a previous launch/graph-replay can never match a step tag.
__global__ __launch_bounds__(256) void k_tagclear(unsigned long long* p, int n) {
  int i = blockIdx.x * 256 + threadIdx.x;
  if (i < n) p[i] = 0xFFFFFFFF00000000ULL;
}

// ---------------- QKV projection: (8192 x 4096) @ (4096 x 512) + bias, z selects Q/K/V
__global__ __launch_bounds__(256) void k_qkv(
    const float* __restrict__ x,
    const float* __restrict__ W0, const float* __restrict__ W1, const float* __restrict__ W2,
    const float* __restrict__ b0, const float* __restrict__ b1, const float* __restrict__ b2,
    float* __restrict__ O0, float* __restrict__ O1, float* __restrict__ O2)
{
  __shared__ float As[32][68];  // transposed A tile: As[k][m]
  __shared__ float Bs[32][64];
  const int z = blockIdx.z;
  const float* W    = (z == 0) ? W0 : (z == 1) ? W1 : W2;
  const float* bias = (z == 0) ? b0 : (z == 1) ? b1 : b2;
  float* Out        = (z == 0) ? O0 : (z == 1) ? O1 : O2;
  const int tid = threadIdx.x;
  const int m0 = blockIdx.y * 64, n0 = blockIdx.x * 64;
  const int tm = tid >> 4, tn = tid & 15;
  const int la_m = tid >> 3;
  const int la_k = (tid & 7) << 2;
  const int lb_k = tid >> 4;
  const int lb_n = (tid & 15) << 2;
  float acc[4][4] = {};
  for (int k0 = 0; k0 < DIN; k0 += 32) {
#pragma unroll
    for (int pp = 0; pp < 2; ++pp) {
      int m = la_m + pp * 32;
      float4 v = *(const float4*)(x + (size_t)(m0 + m) * DIN + k0 + la_k);
      As[la_k + 0][m] = v.x; As[la_k + 1][m] = v.y; As[la_k + 2][m] = v.z; As[la_k + 3][m] = v.w;
    }
#pragma unroll
    for (int pp = 0; pp < 2; ++pp) {
      int k = lb_k + pp * 16;
      *(float4*)&Bs[k][lb_n] = *(const float4*)(W + (size_t)(k0 + k) * P + n0 + lb_n);
    }
    __syncthreads();
#pragma unroll
    for (int kk = 0; kk < 32; ++kk) {
      float4 af = *(float4*)&As[kk][tm << 2];
      float4 bf = *(float4*)&Bs[kk][tn << 2];
      INNER16
    }
    __syncthreads();
  }
  float4 bv = *(const float4*)(bias + n0 + (tn << 2));
#pragma unroll
  for (int i = 0; i < 4; ++i) {
    int row = m0 + (tm << 2) + i;
    float4 o = make_float4(acc[i][0] + bv.x, acc[i][1] + bv.y, acc[i][2] + bv.z, acc[i][3] + bv.w);
    *(float4*)(Out + (size_t)row * P + n0 + (tn << 2)) = o;
  }
}

// ---------------- scores = Q @ K^T / scale, causal mask (only tiles jt <= qt computed)
__global__ __launch_bounds__(256) void k_scores(
    const float* __restrict__ Q, const float* __restrict__ Km, float* __restrict__ Sc)
{
  const int jt = blockIdx.x, qt = blockIdx.y, b = blockIdx.z;
  if (jt > qt) return;
  __shared__ float As[32][68];  // Q^T: As[k][i]
  __shared__ float Bs[32][68];  // K^T: Bs[k][j]
  const float* Qb = Q + (size_t)b * S * P;
  const float* Kb = Km + (size_t)b * S * P;
  const int tid = threadIdx.x;
  const int i0 = qt * 64, j0 = jt * 64;
  const int tm = tid >> 4, tn = tid & 15;
  const int lr = tid >> 3;
  const int lk = (tid & 7) << 2;
  float acc[4][4] = {};
  for (int k0 = 0; k0 < P; k0 += 32) {
#pragma unroll
    for (int pp = 0; pp < 2; ++pp) {
      int r = lr + pp * 32;
      float4 v = *(const float4*)(Qb + (size_t)(i0 + r) * P + k0 + lk);
      As[lk + 0][r] = v.x; As[lk + 1][r] = v.y; As[lk + 2][r] = v.z; As[lk + 3][r] = v.w;
      float4 w = *(const float4*)(Kb + (size_t)(j0 + r) * P + k0 + lk);
      Bs[lk + 0][r] = w.x; Bs[lk + 1][r] = w.y; Bs[lk + 2][r] = w.z; Bs[lk + 3][r] = w.w;
    }
    __syncthreads();
#pragma unroll
    for (int kk = 0; kk < 32; ++kk) {
      float4 af = *(float4*)&As[kk][tm << 2];
      float4 bf = *(float4*)&Bs[kk][tn << 2];
      INNER16
    }
    __syncthreads();
  }
  const float invs = 0.04419417382f;  // 1/sqrt(512+1e-6)
#pragma unroll
  for (int i = 0; i < 4; ++i) {
    int ig = i0 + (tm << 2) + i;
    float v0 = acc[i][0] * invs, v1 = acc[i][1] * invs, v2 = acc[i][2] * invs, v3 = acc[i][3] * invs;
    int jg = j0 + (tn << 2);
    if (jg + 0 > ig) v0 = -1e9f;
    if (jg + 1 > ig) v1 = -1e9f;
    if (jg + 2 > ig) v2 = -1e9f;
    if (jg + 3 > ig) v3 = -1e9f;
    *(float4*)(Sc + (size_t)b * S * S + (size_t)ig * S + jg) = make_float4(v0, v1, v2, v3);
  }
}

// ---------------- row softmax over [0, i], zero-fill to end of diagonal tile (in place)
__global__ __launch_bounds__(256) void k_softmax(float* __restrict__ Sc)
{
  const int i = blockIdx.x, b = blockIdx.y;
  float* row = Sc + (size_t)b * S * S + (size_t)i * S;
  __shared__ float sv[2048];
  __shared__ float red[256];
  const int tid = threadIdx.x;
  const int len = i + 1;
  float lmax = -1e30f;
  for (int k = tid; k < len; k += 256) { float v = row[k]; sv[k] = v; lmax = fmaxf(lmax, v); }
  red[tid] = lmax; __syncthreads();
  for (int s = 128; s > 0; s >>= 1) { if (tid < s) red[tid] = fmaxf(red[tid], red[tid + s]); __syncthreads(); }
  const float m = red[0]; __syncthreads();
  float lsum = 0.f;
  for (int k = tid; k < len; k += 256) { float e = expf(sv[k] - m); sv[k] = e; lsum += e; }
  red[tid] = lsum; __syncthreads();
  for (int s = 128; s > 0; s >>= 1) { if (tid < s) red[tid] += red[tid + s]; __syncthreads(); }
  const float inv = 1.0f / red[0];
  for (int k = tid; k < len; k += 256) row[k] = sv[k] * inv;
  const int tail = ((i >> 6) + 1) << 6;
  for (int k = len + tid; k < tail; k += 256) row[k] = 0.f;
}

// ---------------- feat = attn @ V (skip upper-triangle tiles)
__global__ __launch_bounds__(256) void k_attnv(
    const float* __restrict__ At, const float* __restrict__ V, float* __restrict__ F)
{
  __shared__ float As[32][68];
  __shared__ float Bs[32][64];
  const int qt = blockIdx.y, b = blockIdx.z;
  const float* Ab = At + (size_t)b * S * S;
  const float* Vb = V + (size_t)b * S * P;
  const int tid = threadIdx.x;
  const int m0 = qt * 64, n0 = blockIdx.x * 64;
  const int tm = tid >> 4, tn = tid & 15;
  const int la_m = tid >> 3;
  const int la_k = (tid & 7) << 2;
  const int lb_k = tid >> 4;
  const int lb_n = (tid & 15) << 2;
  float acc[4][4] = {};
  const int kext = (qt + 1) * 64;
  for (int k0 = 0; k0 < kext; k0 += 32) {
#pragma unroll
    for (int pp = 0; pp < 2; ++pp) {
      int m = la_m + pp * 32;
      float4 v = *(const float4*)(Ab + (size_t)(m0 + m) * S + k0 + la_k);
      As[la_k + 0][m] = v.x; As[la_k + 1][m] = v.y; As[la_k + 2][m] = v.z; As[la_k + 3][m] = v.w;
    }
#pragma unroll
    for (int pp = 0; pp < 2; ++pp) {
      int k = lb_k + pp * 16;
      *(float4*)&Bs[k][lb_n] = *(const float4*)(Vb + (size_t)(k0 + k) * P + n0 + lb_n);
    }
    __syncthreads();
#pragma unroll
    for (int kk = 0; kk < 32; ++kk) {
      float4 af = *(float4*)&As[kk][tm << 2];
      float4 bf = *(float4*)&Bs[kk][tn << 2];
      INNER16
    }
    __syncthreads();
  }
#pragma unroll
  for (int i = 0; i < 4; ++i) {
    int row = m0 + (tm << 2) + i;
    *(float4*)(F + (size_t)b * S * P + (size_t)row * P + n0 + (tn << 2)) =
        make_float4(acc[i][0], acc[i][1], acc[i][2], acc[i][3]);
  }
}

// ---------------- gx = feat_assist @ {Wz,Wr,Wh} + bias; output layout [t][b][j]
__global__ __launch_bounds__(256) void k_gx(
    const float* __restrict__ feat,
    const float* __restrict__ Wz, const float* __restrict__ Wr, const float* __restrict__ Wh,
    const float* __restrict__ bz, const float* __restrict__ br, const float* __restrict__ bh,
    float* __restrict__ gz, float* __restrict__ gr, float* __restrict__ gh)
{
  __shared__ float As[32][68];
  __shared__ float Bs[32][64];
  const int z = blockIdx.z;
  const float* W    = (z == 0) ? Wz : (z == 1) ? Wr : Wh;
  const float* bias = (z == 0) ? bz : (z == 1) ? br : bh;
  float* Out        = (z == 0) ? gz : (z == 1) ? gr : gh;
  const int tid = threadIdx.x;
  const int m0 = blockIdx.y * 64, n0 = blockIdx.x * 64;
  const int bb = m0 / TR;
  const int t0 = m0 - bb * TR;
  const float* Arow = feat + ((size_t)(bb * S + AST + t0)) * P;  // 64 consecutive rows
  const int tm = tid >> 4, tn = tid & 15;
  const int la_m = tid >> 3;
  const int la_k = (tid & 7) << 2;
  const int lb_k = tid >> 4;
  const int lb_n = (tid & 15) << 2;
  float acc[4][4] = {};
  for (int k0 = 0; k0 < P; k0 += 32) {
#pragma unroll
    for (int pp = 0; pp < 2; ++pp) {
      int m = la_m + pp * 32;
      float4 v = *(const float4*)(Arow + (size_t)m * P + k0 + la_k);
      As[la_k + 0][m] = v.x; As[la_k + 1][m] = v.y; As[la_k + 2][m] = v.z; As[la_k + 3][m] = v.w;
    }
#pragma unroll
    for (int pp = 0; pp < 2; ++pp) {
      int k = lb_k + pp * 16;
      *(float4*)&Bs[k][lb_n] = *(const float4*)(W + (size_t)(k0 + k) * P + n0 + lb_n);
    }
    __syncthreads();
#pragma unroll
    for (int kk = 0; kk < 32; ++kk) {
      float4 af = *(float4*)&As[kk][tm << 2];
      float4 bf = *(float4*)&Bs[kk][tn << 2];
      INNER16
    }
    __syncthreads();
  }
  float4 bv = *(const float4*)(bias + n0 + (tn << 2));
#pragma unroll
  for (int i = 0; i < 4; ++i) {
    int t = t0 + (tm << 2) + i;
    float4 o = make_float4(acc[i][0] + bv.x, acc[i][1] + bv.y, acc[i][2] + bv.z, acc[i][3] + bv.w);
    *(float4*)(Out + ((size_t)t * 4 + bb) * P + n0 + (tn << 2)) = o;
  }
}

// ---------------- attention pooling over prefix + h0; writes tagged h(0) (tag=0)
__global__ __launch_bounds__(256) void k_pool(
    const float* __restrict__ feat, const float* __restrict__ Wscore,
    const float* __restrict__ Wp2h, const float* __restrict__ bp2h,
    unsigned long long* __restrict__ hT)
{
  const int b = blockIdx.x;
  const float* fb = feat + (size_t)b * S * P;  // prefix rows 0..511
  __shared__ float sw[512];
  __shared__ float pool[512];
  __shared__ float red[256];
  const int tid = threadIdx.x;
  for (int u = tid; u < 512; u += 256) {
    float s = 0.f;
    for (int p4 = 0; p4 < P; p4 += 4) {
      float4 f = *(const float4*)(fb + (size_t)u * P + p4);
      float4 w = *(const float4*)(Wscore + p4);
      s += f.x * w.x + f.y * w.y + f.z * w.z + f.w * w.w;
    }
    sw[u] = s;
  }
  __syncthreads();
  float lm = fmaxf(sw[tid], sw[tid + 256]);
  red[tid] = lm; __syncthreads();
  for (int s = 128; s > 0; s >>= 1) { if (tid < s) red[tid] = fmaxf(red[tid], red[tid + s]); __syncthreads(); }
  const float m = red[0]; __syncthreads();
  float e0 = expf(sw[tid] - m), e1 = expf(sw[tid + 256] - m);
  sw[tid] = e0; sw[tid + 256] = e1;
  red[tid] = e0 + e1; __syncthreads();
  for (int s = 128; s > 0; s >>= 1) { if (tid < s) red[tid] += red[tid + s]; __syncthreads(); }
  const float inv = 1.0f / red[0];
  __syncthreads();
  sw[tid] *= inv; sw[tid + 256] *= inv;
  __syncthreads();
  for (int p = tid; p < P; p += 256) {
    float a = 0.f;
    for (int u = 0; u < 512; ++u) a += sw[u] * fb[(size_t)u * P + p];
    pool[p] = a;
  }
  __syncthreads();
  for (int j = tid; j < P; j += 256) {
    float a = bp2h[j];
    for (int p = 0; p < P; ++p) a += pool[p] * Wp2h[(size_t)p * P + j];
    // tagged word: tag (hi) = 0, value (lo) = f32 bits of h0
    hT[(size_t)b * 512 + j] = (unsigned long long)__float_as_uint(tanhf(a));
  }
}

// xor-butterfly reduce of 4 batch accumulators across a 2^LOG2N-lane group.
// Result: group-lane l holds acc[l&3] summed over the whole group.
template<int LOG2N>
__device__ __forceinline__ float xreduce4(float a0, float a1, float a2, float a3, int lane)
{
  float s01 = (lane & 1) ? a0 : a1;
  float r01 = __shfl_xor(s01, 1);
  float x0  = ((lane & 1) ? a1 : a0) + r01;
  float s23 = (lane & 1) ? a2 : a3;
  float r23 = __shfl_xor(s23, 1);
  float x2  = ((lane & 1) ? a3 : a2) + r23;
  float s   = (lane & 2) ? x0 : x2;
  float r   = __shfl_xor(s, 2);
  float v   = ((lane & 2) ? x2 : x0) + r;
#pragma unroll
  for (int m = 4; m < (1 << LOG2N); m <<= 1) v += __shfl_xor(v, m);
  return v;
}

// ---------------- persistent GRU scan: 32 WGs x 512 threads, 16 U-columns each.
// Round-3 proven 4-barrier skeleton (B2/B4 drain publishes BEFORE polls begin,
// keeping spin traffic out of the publish-visibility window — round-4 lesson).
// Added on top: U slices in registers (kills LDS bank conflicts), logit work
// off-loop (ho streamed to hist), s_sleep(1) backoff on poll retries (cuts
// LLC contention from spinning).
// Hang-safety: every poll is separated from the same WG's corresponding
// publish stores by a __syncthreads() (vmcnt(0) drain) — a WG can never spin
// on a store it has not yet issued. Depth-2 buffer safety: h(t+2)/rh(t+2)
// publish transitively requires every WG to have consumed h(t)/rh(t).
__global__ __launch_bounds__(512) void k_scan(
    const float* __restrict__ Uz, const float* __restrict__ Ur, const float* __restrict__ Uh,
    const float* __restrict__ gz, const float* __restrict__ gr, const float* __restrict__ gh,
    unsigned long long* __restrict__ hT, unsigned long long* __restrict__ rhT,
    float* __restrict__ hist)
{
  __shared__ float Us[3][2][8][520];
  __shared__ float hb[4][516];
  __shared__ float zloc[16][4];
  __shared__ float hploc[16][4];
  const int wg = blockIdx.x;
  const int tid = threadIdx.x;
  const int j0 = wg * 16;

  for (int idx = tid; idx < 3 * 512 * 16; idx += 512) {
    int mt = idx >> 13;                // 8192 elements per matrix
    int rem = idx & 8191;
    int i = rem >> 4, c = rem & 15;
    const float* U = (mt == 0) ? Uz : (mt == 1) ? Ur : Uh;
    Us[mt][c >> 3][c & 7][i] = U[(size_t)i * P + j0 + c];
  }

  // phase-A role: gate g (0=z,1=r), column cAa (0..15), 16 lanes per column
  const int gA  = tid >> 8;
  const int cAa = (tid >> 4) & 15;
  const int ipA = tid & 15;
  const float* UcA = &Us[gA][cAa >> 3][cAa & 7][0];
  // phase-B role: column cBb (0..15), 32 lanes per column
  const int cBb = tid >> 5;
  const int ipB = tid & 31;
  const float* UcB = &Us[2][cBb >> 3][cBb & 7][0];
  // poll role: 4 consecutive floats, single writer WG
  const int pb = tid >> 7;
  const int pj = (tid << 2) & 511;
  __syncthreads();

  // U slices into registers (one-time LDS -> VGPR; occupancy is LDS-bound,
  // so the extra VGPRs are free)
  float4 uA[8], uB[4];
#pragma unroll
  for (int n = 0; n < 8; ++n) uA[n] = *(const float4*)&UcA[((n << 4) | ipA) << 2];
#pragma unroll
  for (int n = 0; n < 4; ++n) uB[n] = *(const float4*)&UcB[((n << 5) | ipB) << 2];

  for (int t = 0; t < TR; ++t) {
    const int sl = t & 1;
    const unsigned long long wtag = (unsigned long long)(unsigned)t << 32;
    // prefetch gx operands (L2 loads, hidden under the h poll)
    float gxa = 0.f;
    if (ipA < 4) gxa = (gA ? gr : gz)[((size_t)t * 4 + ipA) * P + j0 + cAa];
    float ghv = 0.f;
    if (ipB < 4) ghv = gh[((size_t)t * 4 + ipB) * P + j0 + cBb];

    // gather h(t): poll own 4 tagged words, deposit into hb
    {
      const unsigned long long* src = hT + (size_t)sl * 2048 + ((size_t)tid << 2);
      unsigned long long u0, u1, u2, u3;
      u0 = __hip_atomic_load(src + 0, __ATOMIC_RELAXED, __HIP_MEMORY_SCOPE_AGENT);
      u1 = __hip_atomic_load(src + 1, __ATOMIC_RELAXED, __HIP_MEMORY_SCOPE_AGENT);
      u2 = __hip_atomic_load(src + 2, __ATOMIC_RELAXED, __HIP_MEMORY_SCOPE_AGENT);
      u3 = __hip_atomic_load(src + 3, __ATOMIC_RELAXED, __HIP_MEMORY_SCOPE_AGENT);
      while ((((u0 ^ wtag) | (u1 ^ wtag) | (u2 ^ wtag) | (u3 ^ wtag)) >> 32) != 0ull) {
        __builtin_amdgcn_s_sleep(1);   // backoff: keep the LLC clear for publishes
        u0 = __hip_atomic_load(src + 0, __ATOMIC_RELAXED, __HIP_MEMORY_SCOPE_AGENT);
        u1 = __hip_atomic_load(src + 1, __ATOMIC_RELAXED, __HIP_MEMORY_SCOPE_AGENT);
        u2 = __hip_atomic_load(src + 2, __ATOMIC_RELAXED, __HIP_MEMORY_SCOPE_AGENT);
        u3 = __hip_atomic_load(src + 3, __ATOMIC_RELAXED, __HIP_MEMORY_SCOPE_AGENT);
      }
      *(float4*)&hb[pb][pj] = make_float4(
          __uint_as_float((unsigned)u0), __uint_as_float((unsigned)u1),
          __uint_as_float((unsigned)u2), __uint_as_float((unsigned)u3));
    }
    __syncthreads();   // B1: hb holds h(t)

    // phase A: z,r for this WG's 16 columns (one column per 16-lane group)
    {
      float a0 = 0.f, a1 = 0.f, a2 = 0.f, a3 = 0.f;
#pragma unroll
      for (int n = 0; n < 8; ++n) {
        int off = ((n << 4) | ipA) << 2;
        float4 u   = uA[n];
        float4 h0v = *(const float4*)&hb[0][off];
        float4 h1v = *(const float4*)&hb[1][off];
        float4 h2v = *(const float4*)&hb[2][off];
        float4 h3v = *(const float4*)&hb[3][off];
        a0 += u.x * h0v.x + u.y * h0v.y + u.z * h0v.z + u.w * h0v.w;
        a1 += u.x * h1v.x + u.y * h1v.y + u.z * h1v.z + u.w * h1v.w;
        a2 += u.x * h2v.x + u.y * h2v.y + u.z * h2v.z + u.w * h2v.w;
        a3 += u.x * h3v.x + u.y * h3v.y + u.z * h3v.z + u.w * h3v.w;
      }
      float v = xreduce4<4>(a0, a1, a2, a3, ipA);
      if (ipA < 4) {
        const int b = ipA;
        float s = gxa + v;
        float sg = 1.0f / (1.0f + expf(-s));
        if (gA == 0) {
          zloc[cAa][b] = sg;
        } else {
          float hov = hb[b][j0 + cAa];
          hploc[cAa][b] = hov;
          unsigned long long w = wtag | (unsigned long long)__float_as_uint(sg * hov);
          __hip_atomic_store(rhT + (size_t)sl * 2048 + (size_t)b * 512 + j0 + cAa,
                             w, __ATOMIC_RELAXED, __HIP_MEMORY_SCOPE_AGENT);
        }
      }
      asm volatile("" ::: "memory");  // rh publish stays above the barrier
    }
    __syncthreads();   // B2: zloc/hploc visible; rh stores DRAINED (vmcnt 0);
                       //     all hb(h) reads complete

    // gather rh(t): poll own 4 tagged words, deposit straight into hb
    {
      const unsigned long long* src = rhT + (size_t)sl * 2048 + ((size_t)tid << 2);
      unsigned long long r0, r1, r2, r3;
      r0 = __hip_atomic_load(src + 0, __ATOMIC_RELAXED, __HIP_MEMORY_SCOPE_AGENT);
      r1 = __hip_atomic_load(src + 1, __ATOMIC_RELAXED, __HIP_MEMORY_SCOPE_AGENT);
      r2 = __hip_atomic_load(src + 2, __ATOMIC_RELAXED, __HIP_MEMORY_SCOPE_AGENT);
      r3 = __hip_atomic_load(src + 3, __ATOMIC_RELAXED, __HIP_MEMORY_SCOPE_AGENT);
      while ((((r0 ^ wtag) | (r1 ^ wtag) | (r2 ^ wtag) | (r3 ^ wtag)) >> 32) != 0ull) {
        __builtin_amdgcn_s_sleep(1);
        r0 = __hip_atomic_load(src + 0, __ATOMIC_RELAXED, __HIP_MEMORY_SCOPE_AGENT);
        r1 = __hip_atomic_load(src + 1, __ATOMIC_RELAXED, __HIP_MEMORY_SCOPE_AGENT);
        r2 = __hip_atomic_load(src + 2, __ATOMIC_RELAXED, __HIP_MEMORY_SCOPE_AGENT);
        r3 = __hip_atomic_load(src + 3, __ATOMIC_RELAXED, __HIP_MEMORY_SCOPE_AGENT);
      }
      *(float4*)&hb[pb][pj] = make_float4(
          __uint_as_float((unsigned)r0), __uint_as_float((unsigned)r1),
          __uint_as_float((unsigned)r2), __uint_as_float((unsigned)r3));
    }
    __syncthreads();   // B3: hb holds rh(t)

    // phase B: h_hat, h_new, h_out; publish tagged h(t+1); stream ho to hist
    {
      float p0 = 0.f, p1 = 0.f, p2 = 0.f, p3 = 0.f;
#pragma unroll
      for (int n = 0; n < 4; ++n) {
        int off = ((n << 5) | ipB) << 2;
        float4 u   = uB[n];
        float4 h0v = *(const float4*)&hb[0][off];
        float4 h1v = *(const float4*)&hb[1][off];
        float4 h2v = *(const float4*)&hb[2][off];
        float4 h3v = *(const float4*)&hb[3][off];
        p0 += u.x * h0v.x + u.y * h0v.y + u.z * h0v.z + u.w * h0v.w;
        p1 += u.x * h1v.x + u.y * h1v.y + u.z * h1v.z + u.w * h1v.w;
        p2 += u.x * h2v.x + u.y * h2v.y + u.z * h2v.z + u.w * h2v.w;
        p3 += u.x * h3v.x + u.y * h3v.y + u.z * h3v.z + u.w * h3v.w;
      }
      float pv = xreduce4<5>(p0, p1, p2, p3, ipB);
      if (ipB < 4) {
        const int b = ipB;
        float hhat = tanhf(ghv + pv);
        float z = zloc[cBb][b], hp = hploc[cBb][b];
        float hn = (1.0f - z) * hp + z * hhat;
        float dtv = (t == 0) ? 0.f : DTC;
        float ho = hn + dtv * (hn - hp);
        unsigned long long w = ((unsigned long long)(unsigned)(t + 1) << 32)
                             | (unsigned long long)__float_as_uint(ho);
        __hip_atomic_store(hT + (size_t)((t + 1) & 1) * 2048 + (size_t)b * 512 + j0 + cBb,
                           w, __ATOMIC_RELAXED, __HIP_MEMORY_SCOPE_AGENT);
        hist[((size_t)t * 4 + b) * 512 + j0 + cBb] = ho;   // fire-and-forget
      }
      asm volatile("" ::: "memory");  // h publish stays above the barrier
    }
    __syncthreads();   // B4: h(t+1) stores DRAINED; all hb(rh) reads complete
  }
}

// ---------------- final logits: out[b][t] = bmem + hist[t,b,:] @ Wmem
__global__ __launch_bounds__(256) void k_outred(
    const float* __restrict__ hist, const float* __restrict__ Wmem,
    const float* __restrict__ bmem, float* __restrict__ out)
{
  int i = blockIdx.x * 256 + threadIdx.x;
  if (i < Bb * TR) {
    int b = i / TR, t = i - b * TR;
    const float* hrow = hist + ((size_t)t * 4 + b) * 512;
    float s = 0.f;
    for (int j = 0; j < 512; j += 4) {
      float4 h = *(const float4*)(hrow + j);
      float4 w = *(const float4*)(Wmem + j);
      s += h.x * w.x + h.y * w.y + h.z * w.z + h.w * w.w;
    }
    out[i] = s + bmem[0];
  }
}

extern "C" void kernel_launch(void* const* d_in, const int* in_sizes, int n_in,
                              void* d_out, int out_size, void* d_ws, size_t ws_size,
                              hipStream_t stream)
{
  const float* x      = (const float*)d_in[0];
  const float* Wq     = (const float*)d_in[1];
  const float* bq     = (const float*)d_in[2];
  const float* Wk     = (const float*)d_in[3];
  const float* bk     = (const float*)d_in[4];
  const float* Wv     = (const float*)d_in[5];
  const float* bv     = (const float*)d_in[6];
  const float* Wz     = (const float*)d_in[7];
  const float* Uz     = (const float*)d_in[8];
  const float* bz     = (const float*)d_in[9];
  const float* Wr     = (const float*)d_in[10];
  const float* Ur     = (const float*)d_in[11];
  const float* br     = (const float*)d_in[12];
  const float* Wh     = (const float*)d_in[13];
  const float* Uh     = (const float*)d_in[14];
  const float* bh     = (const float*)d_in[15];
  const float* Wmem   = (const float*)d_in[16];
  const float* bmem   = (const float*)d_in[17];
  const float* Wp2h   = (const float*)d_in[18];
  const float* bp2h   = (const float*)d_in[19];
  const float* Wscore = (const float*)d_in[20];

  float* ws  = (float*)d_ws;
  float* out = (float*)d_out;
  float* Q    = ws + OFF_Q;
  float* Kk   = ws + OFF_K;
  float* V    = ws + OFF_V;
  float* feat = ws + OFF_FEAT;
  float* Sc   = ws + OFF_SC;
  float* gz   = ws + OFF_GXZ;
  float* gr   = ws + OFF_GXR;
  float* gh   = ws + OFF_GXH;
  // Tagged sync buffers + ho history live at the head of the
  // (dead-after-attnv) scores region.
  unsigned long long* hT   = (unsigned long long*)(ws + OFF_SC);
  unsigned long long* rhT  = hT + 4096;
  float*              hist = ws + OFF_HIST;

  k_qkv<<<dim3(8, 128, 3), 256, 0, stream>>>(x, Wq, Wk, Wv, bq, bk, bv, Q, Kk, V);
  k_scores<<<dim3(32, 32, 4), 256, 0, stream>>>(Q, Kk, Sc);
  k_softmax<<<dim3(2048, 4), 256, 0, stream>>>(Sc);
  k_attnv<<<dim3(8, 32, 4), 256, 0, stream>>>(Sc, V, feat);
  // clear stale tags AFTER the scores region is dead, BEFORE k_pool writes h0
  k_tagclear<<<dim3(32), 256, 0, stream>>>(hT, 8192);
  k_gx<<<dim3(8, 96, 3), 256, 0, stream>>>(feat, Wz, Wr, Wh, bz, br, bh, gz, gr, gh);
  k_pool<<<dim3(4), 256, 0, stream>>>(feat, Wscore, Wp2h, bp2h, hT);
  k_scan<<<dim3(NWG), 512, 0, stream>>>(Uz, Ur, Uh, gz, gr, gh, hT, rhT, hist);
  k_outred<<<dim3(24), 256, 0, stream>>>(hist, Wmem, bmem, out);
}

// Round 6
// 7450.612 us; speedup vs baseline: 1.4473x; 1.2510x over previous
//
#include <hip/hip_runtime.h>
#include <cmath>

// Problem constants
static constexpr int Bb  = 4;
static constexpr int S   = 2048;
static constexpr int DIN = 4096;
static constexpr int P   = 512;    // D_PROJ == D_MEM
static constexpr int AST = 512;    // assistant_start
static constexpr int TR  = 1536;   // run length
static constexpr int NWG = 128;    // scan WGs: 4 batch-groups x 32 column-slices
#define DTC (1.0f/1535.0f)

// Workspace layout (float element offsets)
static constexpr size_t SZ      = (size_t)Bb * S * P;          // 4,194,304
static constexpr size_t GXSZ    = (size_t)TR * Bb * P;         // 3,145,728
static constexpr size_t OFF_Q   = 0;
static constexpr size_t OFF_K   = SZ;
static constexpr size_t OFF_V   = 2 * SZ;
static constexpr size_t OFF_GXZ = 0;                           // reuses Q/K/V after attention
static constexpr size_t OFF_GXR = GXSZ;
static constexpr size_t OFF_GXH = 2 * GXSZ;
static constexpr size_t OFF_FEAT= 3 * GXSZ + (size_t)(TR + 1) * Bb * P;
static constexpr size_t OFF_SC  = OFF_FEAT + SZ;               // scores; tagged bufs + hist live here in scan phase
static constexpr size_t OFF_HIST= OFF_SC + 16384;              // after hT/rhT (8192 u64 = 16384 floats)

#define INNER16 \
  acc[0][0] += af.x*bf.x; acc[0][1] += af.x*bf.y; acc[0][2] += af.x*bf.z; acc[0][3] += af.x*bf.w; \
  acc[1][0] += af.y*bf.x; acc[1][1] += af.y*bf.y; acc[1][2] += af.y*bf.z; acc[1][3] += af.y*bf.w; \
  acc[2][0] += af.z*bf.x; acc[2][1] += af.z*bf.y; acc[2][2] += af.z*bf.z; acc[2][3] += af.z*bf.w; \
  acc[3][0] += af.w*bf.x; acc[3][1] += af.w*bf.y; acc[3][2] += af.w*bf.z; acc[3][3] += af.w*bf.w;

// Fill tagged-word buffers with an impossible tag (0xFFFFFFFF) so stale data
// from a previous launch/graph-replay can never match a step tag.
__global__ __launch_bounds__(256) void k_tagclear(unsigned long long* p, int n) {
  int i = blockIdx.x * 256 + threadIdx.x;
  if (i < n) p[i] = 0xFFFFFFFF00000000ULL;
}

// ---------------- QKV projection: (8192 x 4096) @ (4096 x 512) + bias, z selects Q/K/V
__global__ __launch_bounds__(256) void k_qkv(
    const float* __restrict__ x,
    const float* __restrict__ W0, const float* __restrict__ W1, const float* __restrict__ W2,
    const float* __restrict__ b0, const float* __restrict__ b1, const float* __restrict__ b2,
    float* __restrict__ O0, float* __restrict__ O1, float* __restrict__ O2)
{
  __shared__ float As[32][68];  // transposed A tile: As[k][m]
  __shared__ float Bs[32][64];
  const int z = blockIdx.z;
  const float* W    = (z == 0) ? W0 : (z == 1) ? W1 : W2;
  const float* bias = (z == 0) ? b0 : (z == 1) ? b1 : b2;
  float* Out        = (z == 0) ? O0 : (z == 1) ? O1 : O2;
  const int tid = threadIdx.x;
  const int m0 = blockIdx.y * 64, n0 = blockIdx.x * 64;
  const int tm = tid >> 4, tn = tid & 15;
  const int la_m = tid >> 3;
  const int la_k = (tid & 7) << 2;
  const int lb_k = tid >> 4;
  const int lb_n = (tid & 15) << 2;
  float acc[4][4] = {};
  for (int k0 = 0; k0 < DIN; k0 += 32) {
#pragma unroll
    for (int pp = 0; pp < 2; ++pp) {
      int m = la_m + pp * 32;
      float4 v = *(const float4*)(x + (size_t)(m0 + m) * DIN + k0 + la_k);
      As[la_k + 0][m] = v.x; As[la_k + 1][m] = v.y; As[la_k + 2][m] = v.z; As[la_k + 3][m] = v.w;
    }
#pragma unroll
    for (int pp = 0; pp < 2; ++pp) {
      int k = lb_k + pp * 16;
      *(float4*)&Bs[k][lb_n] = *(const float4*)(W + (size_t)(k0 + k) * P + n0 + lb_n);
    }
    __syncthreads();
#pragma unroll
    for (int kk = 0; kk < 32; ++kk) {
      float4 af = *(float4*)&As[kk][tm << 2];
      float4 bf = *(float4*)&Bs[kk][tn << 2];
      INNER16
    }
    __syncthreads();
  }
  float4 bv = *(const float4*)(bias + n0 + (tn << 2));
#pragma unroll
  for (int i = 0; i < 4; ++i) {
    int row = m0 + (tm << 2) + i;
    float4 o = make_float4(acc[i][0] + bv.x, acc[i][1] + bv.y, acc[i][2] + bv.z, acc[i][3] + bv.w);
    *(float4*)(Out + (size_t)row * P + n0 + (tn << 2)) = o;
  }
}

// ---------------- scores = Q @ K^T / scale, causal mask (only tiles jt <= qt computed)
__global__ __launch_bounds__(256) void k_scores(
    const float* __restrict__ Q, const float* __restrict__ Km, float* __restrict__ Sc)
{
  const int jt = blockIdx.x, qt = blockIdx.y, b = blockIdx.z;
  if (jt > qt) return;
  __shared__ float As[32][68];  // Q^T: As[k][i]
  __shared__ float Bs[32][68];  // K^T: Bs[k][j]
  const float* Qb = Q + (size_t)b * S * P;
  const float* Kb = Km + (size_t)b * S * P;
  const int tid = threadIdx.x;
  const int i0 = qt * 64, j0 = jt * 64;
  const int tm = tid >> 4, tn = tid & 15;
  const int lr = tid >> 3;
  const int lk = (tid & 7) << 2;
  float acc[4][4] = {};
  for (int k0 = 0; k0 < P; k0 += 32) {
#pragma unroll
    for (int pp = 0; pp < 2; ++pp) {
      int r = lr + pp * 32;
      float4 v = *(const float4*)(Qb + (size_t)(i0 + r) * P + k0 + lk);
      As[lk + 0][r] = v.x; As[lk + 1][r] = v.y; As[lk + 2][r] = v.z; As[lk + 3][r] = v.w;
      float4 w = *(const float4*)(Kb + (size_t)(j0 + r) * P + k0 + lk);
      Bs[lk + 0][r] = w.x; Bs[lk + 1][r] = w.y; Bs[lk + 2][r] = w.z; Bs[lk + 3][r] = w.w;
    }
    __syncthreads();
#pragma unroll
    for (int kk = 0; kk < 32; ++kk) {
      float4 af = *(float4*)&As[kk][tm << 2];
      float4 bf = *(float4*)&Bs[kk][tn << 2];
      INNER16
    }
    __syncthreads();
  }
  const float invs = 0.04419417382f;  // 1/sqrt(512+1e-6)
#pragma unroll
  for (int i = 0; i < 4; ++i) {
    int ig = i0 + (tm << 2) + i;
    float v0 = acc[i][0] * invs, v1 = acc[i][1] * invs, v2 = acc[i][2] * invs, v3 = acc[i][3] * invs;
    int jg = j0 + (tn << 2);
    if (jg + 0 > ig) v0 = -1e9f;
    if (jg + 1 > ig) v1 = -1e9f;
    if (jg + 2 > ig) v2 = -1e9f;
    if (jg + 3 > ig) v3 = -1e9f;
    *(float4*)(Sc + (size_t)b * S * S + (size_t)ig * S + jg) = make_float4(v0, v1, v2, v3);
  }
}

// ---------------- row softmax over [0, i], zero-fill to end of diagonal tile (in place)
__global__ __launch_bounds__(256) void k_softmax(float* __restrict__ Sc)
{
  const int i = blockIdx.x, b = blockIdx.y;
  float* row = Sc + (size_t)b * S * S + (size_t)i * S;
  __shared__ float sv[2048];
  __shared__ float red[256];
  const int tid = threadIdx.x;
  const int len = i + 1;
  float lmax = -1e30f;
  for (int k = tid; k < len; k += 256) { float v = row[k]; sv[k] = v; lmax = fmaxf(lmax, v); }
  red[tid] = lmax; __syncthreads();
  for (int s = 128; s > 0; s >>= 1) { if (tid < s) red[tid] = fmaxf(red[tid], red[tid + s]); __syncthreads(); }
  const float m = red[0]; __syncthreads();
  float lsum = 0.f;
  for (int k = tid; k < len; k += 256) { float e = expf(sv[k] - m); sv[k] = e; lsum += e; }
  red[tid] = lsum; __syncthreads();
  for (int s = 128; s > 0; s >>= 1) { if (tid < s) red[tid] += red[tid + s]; __syncthreads(); }
  const float inv = 1.0f / red[0];
  for (int k = tid; k < len; k += 256) row[k] = sv[k] * inv;
  const int tail = ((i >> 6) + 1) << 6;
  for (int k = len + tid; k < tail; k += 256) row[k] = 0.f;
}

// ---------------- feat = attn @ V (skip upper-triangle tiles)
__global__ __launch_bounds__(256) void k_attnv(
    const float* __restrict__ At, const float* __restrict__ V, float* __restrict__ F)
{
  __shared__ float As[32][68];
  __shared__ float Bs[32][64];
  const int qt = blockIdx.y, b = blockIdx.z;
  const float* Ab = At + (size_t)b * S * S;
  const float* Vb = V + (size_t)b * S * P;
  const int tid = threadIdx.x;
  const int m0 = qt * 64, n0 = blockIdx.x * 64;
  const int tm = tid >> 4, tn = tid & 15;
  const int la_m = tid >> 3;
  const int la_k = (tid & 7) << 2;
  const int lb_k = tid >> 4;
  const int lb_n = (tid & 15) << 2;
  float acc[4][4] = {};
  const int kext = (qt + 1) * 64;
  for (int k0 = 0; k0 < kext; k0 += 32) {
#pragma unroll
    for (int pp = 0; pp < 2; ++pp) {
      int m = la_m + pp * 32;
      float4 v = *(const float4*)(Ab + (size_t)(m0 + m) * S + k0 + la_k);
      As[la_k + 0][m] = v.x; As[la_k + 1][m] = v.y; As[la_k + 2][m] = v.z; As[la_k + 3][m] = v.w;
    }
#pragma unroll
    for (int pp = 0; pp < 2; ++pp) {
      int k = lb_k + pp * 16;
      *(float4*)&Bs[k][lb_n] = *(const float4*)(Vb + (size_t)(k0 + k) * P + n0 + lb_n);
    }
    __syncthreads();
#pragma unroll
    for (int kk = 0; kk < 32; ++kk) {
      float4 af = *(float4*)&As[kk][tm << 2];
      float4 bf = *(float4*)&Bs[kk][tn << 2];
      INNER16
    }
    __syncthreads();
  }
#pragma unroll
  for (int i = 0; i < 4; ++i) {
    int row = m0 + (tm << 2) + i;
    *(float4*)(F + (size_t)b * S * P + (size_t)row * P + n0 + (tn << 2)) =
        make_float4(acc[i][0], acc[i][1], acc[i][2], acc[i][3]);
  }
}

// ---------------- gx = feat_assist @ {Wz,Wr,Wh} + bias; output layout [t][b][j]
__global__ __launch_bounds__(256) void k_gx(
    const float* __restrict__ feat,
    const float* __restrict__ Wz, const float* __restrict__ Wr, const float* __restrict__ Wh,
    const float* __restrict__ bz, const float* __restrict__ br, const float* __restrict__ bh,
    float* __restrict__ gz, float* __restrict__ gr, float* __restrict__ gh)
{
  __shared__ float As[32][68];
  __shared__ float Bs[32][64];
  const int z = blockIdx.z;
  const float* W    = (z == 0) ? Wz : (z == 1) ? Wr : Wh;
  const float* bias = (z == 0) ? bz : (z == 1) ? br : bh;
  float* Out        = (z == 0) ? gz : (z == 1) ? gr : gh;
  const int tid = threadIdx.x;
  const int m0 = blockIdx.y * 64, n0 = blockIdx.x * 64;
  const int bb = m0 / TR;
  const int t0 = m0 - bb * TR;
  const float* Arow = feat + ((size_t)(bb * S + AST + t0)) * P;  // 64 consecutive rows
  const int tm = tid >> 4, tn = tid & 15;
  const int la_m = tid >> 3;
  const int la_k = (tid & 7) << 2;
  const int lb_k = tid >> 4;
  const int lb_n = (tid & 15) << 2;
  float acc[4][4] = {};
  for (int k0 = 0; k0 < P; k0 += 32) {
#pragma unroll
    for (int pp = 0; pp < 2; ++pp) {
      int m = la_m + pp * 32;
      float4 v = *(const float4*)(Arow + (size_t)m * P + k0 + la_k);
      As[la_k + 0][m] = v.x; As[la_k + 1][m] = v.y; As[la_k + 2][m] = v.z; As[la_k + 3][m] = v.w;
    }
#pragma unroll
    for (int pp = 0; pp < 2; ++pp) {
      int k = lb_k + pp * 16;
      *(float4*)&Bs[k][lb_n] = *(const float4*)(W + (size_t)(k0 + k) * P + n0 + lb_n);
    }
    __syncthreads();
#pragma unroll
    for (int kk = 0; kk < 32; ++kk) {
      float4 af = *(float4*)&As[kk][tm << 2];
      float4 bf = *(float4*)&Bs[kk][tn << 2];
      INNER16
    }
    __syncthreads();
  }
  float4 bv = *(const float4*)(bias + n0 + (tn << 2));
#pragma unroll
  for (int i = 0; i < 4; ++i) {
    int t = t0 + (tm << 2) + i;
    float4 o = make_float4(acc[i][0] + bv.x, acc[i][1] + bv.y, acc[i][2] + bv.z, acc[i][3] + bv.w);
    *(float4*)(Out + ((size_t)t * 4 + bb) * P + n0 + (tn << 2)) = o;
  }
}

// ---------------- attention pooling over prefix + h0; writes tagged h(0) (tag=0)
// into batch-group b's buffer: hT[b][slot 0][j]
__global__ __launch_bounds__(256) void k_pool(
    const float* __restrict__ feat, const float* __restrict__ Wscore,
    const float* __restrict__ Wp2h, const float* __restrict__ bp2h,
    unsigned long long* __restrict__ hT)
{
  const int b = blockIdx.x;
  const float* fb = feat + (size_t)b * S * P;  // prefix rows 0..511
  __shared__ float sw[512];
  __shared__ float pool[512];
  __shared__ float red[256];
  const int tid = threadIdx.x;
  for (int u = tid; u < 512; u += 256) {
    float s = 0.f;
    for (int p4 = 0; p4 < P; p4 += 4) {
      float4 f = *(const float4*)(fb + (size_t)u * P + p4);
      float4 w = *(const float4*)(Wscore + p4);
      s += f.x * w.x + f.y * w.y + f.z * w.z + f.w * w.w;
    }
    sw[u] = s;
  }
  __syncthreads();
  float lm = fmaxf(sw[tid], sw[tid + 256]);
  red[tid] = lm; __syncthreads();
  for (int s = 128; s > 0; s >>= 1) { if (tid < s) red[tid] = fmaxf(red[tid], red[tid + s]); __syncthreads(); }
  const float m = red[0]; __syncthreads();
  float e0 = expf(sw[tid] - m), e1 = expf(sw[tid + 256] - m);
  sw[tid] = e0; sw[tid + 256] = e1;
  red[tid] = e0 + e1; __syncthreads();
  for (int s = 128; s > 0; s >>= 1) { if (tid < s) red[tid] += red[tid + s]; __syncthreads(); }
  const float inv = 1.0f / red[0];
  __syncthreads();
  sw[tid] *= inv; sw[tid + 256] *= inv;
  __syncthreads();
  for (int p = tid; p < P; p += 256) {
    float a = 0.f;
    for (int u = 0; u < 512; ++u) a += sw[u] * fb[(size_t)u * P + p];
    pool[p] = a;
  }
  __syncthreads();
  for (int j = tid; j < P; j += 256) {
    float a = bp2h[j];
    for (int p = 0; p < P; ++p) a += pool[p] * Wp2h[(size_t)p * P + j];
    // tagged word: tag (hi) = 0, value (lo) = f32 bits of h0; group b, slot 0
    hT[(size_t)b * 1024 + j] = (unsigned long long)__float_as_uint(tanhf(a));
  }
}

// ---------------- persistent GRU scan: 4 batch-groups x 32 WGs x 512 threads.
// Group g runs batch g's recurrence independently (disjoint tagged buffers),
// with the same round-3/5-proven 4-barrier skeleton per group:
//   poll h -> B1 -> phase A (publish rh) -> B2(drain) -> poll rh -> B3 ->
//   phase B (publish h(t+1), stream ho to hist) -> B4(drain).
// Each thread polls exactly ONE tagged word (512 words, 512 threads).
// Per-batch arithmetic order identical to prior rounds (serial n-sum +
// lane butterfly). U slices in registers; s_sleep backoff on retries.
// Hang-safety: own-column h/rh stores of a slot are drained by B4/B2 before
// any same-slot poll; groups never touch each other's words.
__global__ __launch_bounds__(512) void k_scan(
    const float* __restrict__ Uz, const float* __restrict__ Ur, const float* __restrict__ Uh,
    const float* __restrict__ gz, const float* __restrict__ gr, const float* __restrict__ gh,
    unsigned long long* __restrict__ hT, unsigned long long* __restrict__ rhT,
    float* __restrict__ hist)
{
  __shared__ float Us[3][2][8][520];
  __shared__ float hb[512];
  __shared__ float zloc[16];
  __shared__ float hploc[16];
  const int bid = blockIdx.x;
  const int g   = bid & 3;          // batch group
  const int w   = bid >> 2;         // column-slice WG within group
  const int tid = threadIdx.x;
  const int j0  = w * 16;
  unsigned long long* hTg  = hT  + (size_t)g * 1024;   // [2 slots][512]
  unsigned long long* rhTg = rhT + (size_t)g * 1024;

  for (int idx = tid; idx < 3 * 512 * 16; idx += 512) {
    int mt = idx >> 13;                // 8192 elements per matrix
    int rem = idx & 8191;
    int i = rem >> 4, c = rem & 15;
    const float* U = (mt == 0) ? Uz : (mt == 1) ? Ur : Uh;
    Us[mt][c >> 3][c & 7][i] = U[(size_t)i * P + j0 + c];
  }

  // phase-A role: gate gA (0=z,1=r), column cAa (0..15), 16 lanes per column
  const int gA  = tid >> 8;
  const int cAa = (tid >> 4) & 15;
  const int ipA = tid & 15;
  const float* UcA = &Us[gA][cAa >> 3][cAa & 7][0];
  // phase-B role: column cBb (0..15), 32 lanes per column
  const int cBb = tid >> 5;
  const int ipB = tid & 31;
  const float* UcB = &Us[2][cBb >> 3][cBb & 7][0];
  __syncthreads();

  // U slices into registers (one-time LDS -> VGPR)
  float4 uA[8], uB[4];
#pragma unroll
  for (int n = 0; n < 8; ++n) uA[n] = *(const float4*)&UcA[((n << 4) | ipA) << 2];
#pragma unroll
  for (int n = 0; n < 4; ++n) uB[n] = *(const float4*)&UcB[((n << 5) | ipB) << 2];

  for (int t = 0; t < TR; ++t) {
    const int sl = t & 1;
    const unsigned tg = (unsigned)t;
    // prefetch gx operands (L2 loads, hidden under the h poll)
    float gxa = 0.f;
    if (ipA == 0) gxa = (gA ? gr : gz)[((size_t)t * 4 + g) * P + j0 + cAa];
    float ghv = 0.f;
    if (ipB == 0) ghv = gh[((size_t)t * 4 + g) * P + j0 + cBb];

    // gather h(t): poll own single tagged word, deposit into hb
    {
      const unsigned long long* src = hTg + (size_t)sl * 512 + tid;
      unsigned long long u = __hip_atomic_load(src, __ATOMIC_RELAXED, __HIP_MEMORY_SCOPE_AGENT);
      while ((unsigned)(u >> 32) != tg) {
        __builtin_amdgcn_s_sleep(1);   // backoff: keep the LLC clear for publishes
        u = __hip_atomic_load(src, __ATOMIC_RELAXED, __HIP_MEMORY_SCOPE_AGENT);
      }
      hb[tid] = __uint_as_float((unsigned)u);
    }
    __syncthreads();   // B1: hb holds h(t) for batch g

    // phase A: z,r for this WG's 16 columns (one column-gate per 16-lane group)
    {
      float a0 = 0.f;
#pragma unroll
      for (int n = 0; n < 8; ++n) {
        int off = ((n << 4) | ipA) << 2;
        float4 u  = uA[n];
        float4 hv = *(const float4*)&hb[off];
        a0 += u.x * hv.x + u.y * hv.y + u.z * hv.z + u.w * hv.w;
      }
      a0 += __shfl_xor(a0, 1);
      a0 += __shfl_xor(a0, 2);
      a0 += __shfl_xor(a0, 4);
      a0 += __shfl_xor(a0, 8);
      if (ipA == 0) {
        float s = gxa + a0;
        float sg = 1.0f / (1.0f + expf(-s));
        if (gA == 0) {
          zloc[cAa] = sg;
        } else {
          float hov = hb[j0 + cAa];
          hploc[cAa] = hov;
          unsigned long long wv = ((unsigned long long)tg << 32)
                                | (unsigned long long)__float_as_uint(sg * hov);
          __hip_atomic_store(rhTg + (size_t)sl * 512 + j0 + cAa,
                             wv, __ATOMIC_RELAXED, __HIP_MEMORY_SCOPE_AGENT);
        }
      }
      asm volatile("" ::: "memory");  // rh publish stays above the barrier
    }
    __syncthreads();   // B2: zloc/hploc visible; rh stores DRAINED (vmcnt 0);
                       //     all hb(h) reads complete

    // gather rh(t): poll own single tagged word, deposit straight into hb
    {
      const unsigned long long* src = rhTg + (size_t)sl * 512 + tid;
      unsigned long long r = __hip_atomic_load(src, __ATOMIC_RELAXED, __HIP_MEMORY_SCOPE_AGENT);
      while ((unsigned)(r >> 32) != tg) {
        __builtin_amdgcn_s_sleep(1);
        r = __hip_atomic_load(src, __ATOMIC_RELAXED, __HIP_MEMORY_SCOPE_AGENT);
      }
      hb[tid] = __uint_as_float((unsigned)r);
    }
    __syncthreads();   // B3: hb holds rh(t)

    // phase B: h_hat, h_new, h_out; publish tagged h(t+1); stream ho to hist
    {
      float p0 = 0.f;
#pragma unroll
      for (int n = 0; n < 4; ++n) {
        int off = ((n << 5) | ipB) << 2;
        float4 u  = uB[n];
        float4 hv = *(const float4*)&hb[off];
        p0 += u.x * hv.x + u.y * hv.y + u.z * hv.z + u.w * hv.w;
      }
      p0 += __shfl_xor(p0, 1);
      p0 += __shfl_xor(p0, 2);
      p0 += __shfl_xor(p0, 4);
      p0 += __shfl_xor(p0, 8);
      p0 += __shfl_xor(p0, 16);
      if (ipB == 0) {
        float hhat = tanhf(ghv + p0);
        float z = zloc[cBb], hp = hploc[cBb];
        float hn = (1.0f - z) * hp + z * hhat;
        float dtv = (t == 0) ? 0.f : DTC;
        float ho = hn + dtv * (hn - hp);
        unsigned long long wv = ((unsigned long long)(unsigned)(t + 1) << 32)
                              | (unsigned long long)__float_as_uint(ho);
        __hip_atomic_store(hTg + (size_t)((t + 1) & 1) * 512 + j0 + cBb,
                           wv, __ATOMIC_RELAXED, __HIP_MEMORY_SCOPE_AGENT);
        hist[((size_t)t * 4 + g) * 512 + j0 + cBb] = ho;   // fire-and-forget
      }
      asm volatile("" ::: "memory");  // h publish stays above the barrier
    }
    __syncthreads();   // B4: h(t+1) stores DRAINED; all hb(rh) reads complete
  }
}

// ---------------- final logits: out[b][t] = bmem + hist[t,b,:] @ Wmem
__global__ __launch_bounds__(256) void k_outred(
    const float* __restrict__ hist, const float* __restrict__ Wmem,
    const float* __restrict__ bmem, float* __restrict__ out)
{
  int i = blockIdx.x * 256 + threadIdx.x;
  if (i < Bb * TR) {
    int b = i / TR, t = i - b * TR;
    const float* hrow = hist + ((size_t)t * 4 + b) * 512;
    float s = 0.f;
    for (int j = 0; j < 512; j += 4) {
      float4 h = *(const float4*)(hrow + j);
      float4 w = *(const float4*)(Wmem + j);
      s += h.x * w.x + h.y * w.y + h.z * w.z + h.w * w.w;
    }
    out[i] = s + bmem[0];
  }
}

extern "C" void kernel_launch(void* const* d_in, const int* in_sizes, int n_in,
                              void* d_out, int out_size, void* d_ws, size_t ws_size,
                              hipStream_t stream)
{
  const float* x      = (const float*)d_in[0];
  const float* Wq     = (const float*)d_in[1];
  const float* bq     = (const float*)d_in[2];
  const float* Wk     = (const float*)d_in[3];
  const float* bk     = (const float*)d_in[4];
  const float* Wv     = (const float*)d_in[5];
  const float* bv     = (const float*)d_in[6];
  const float* Wz     = (const float*)d_in[7];
  const float* Uz     = (const float*)d_in[8];
  const float* bz     = (const float*)d_in[9];
  const float* Wr     = (const float*)d_in[10];
  const float* Ur     = (const float*)d_in[11];
  const float* br     = (const float*)d_in[12];
  const float* Wh     = (const float*)d_in[13];
  const float* Uh     = (const float*)d_in[14];
  const float* bh     = (const float*)d_in[15];
  const float* Wmem   = (const float*)d_in[16];
  const float* bmem   = (const float*)d_in[17];
  const float* Wp2h   = (const float*)d_in[18];
  const float* bp2h   = (const float*)d_in[19];
  const float* Wscore = (const float*)d_in[20];

  float* ws  = (float*)d_ws;
  float* out = (float*)d_out;
  float* Q    = ws + OFF_Q;
  float* Kk   = ws + OFF_K;
  float* V    = ws + OFF_V;
  float* feat = ws + OFF_FEAT;
  float* Sc   = ws + OFF_SC;
  float* gz   = ws + OFF_GXZ;
  float* gr   = ws + OFF_GXR;
  float* gh   = ws + OFF_GXH;
  // Tagged sync buffers (per-group: [4][2][512] each) + ho history live at
  // the head of the (dead-after-attnv) scores region.
  unsigned long long* hT   = (unsigned long long*)(ws + OFF_SC);
  unsigned long long* rhT  = hT + 4096;
  float*              hist = ws + OFF_HIST;

  k_qkv<<<dim3(8, 128, 3), 256, 0, stream>>>(x, Wq, Wk, Wv, bq, bk, bv, Q, Kk, V);
  k_scores<<<dim3(32, 32, 4), 256, 0, stream>>>(Q, Kk, Sc);
  k_softmax<<<dim3(2048, 4), 256, 0, stream>>>(Sc);
  k_attnv<<<dim3(8, 32, 4), 256, 0, stream>>>(Sc, V, feat);
  // clear stale tags AFTER the scores region is dead, BEFORE k_pool writes h0
  k_tagclear<<<dim3(32), 256, 0, stream>>>(hT, 8192);
  k_gx<<<dim3(8, 96, 3), 256, 0, stream>>>(feat, Wz, Wr, Wh, bz, br, bh, gz, gr, gh);
  k_pool<<<dim3(4), 256, 0, stream>>>(feat, Wscore, Wp2h, bp2h, hT);
  k_scan<<<dim3(NWG), 512, 0, stream>>>(Uz, Ur, Uh, gz, gr, gh, hT, rhT, hist);
  k_outred<<<dim3(24), 256, 0, stream>>>(hist, Wmem, bmem, out);
}